// Round 9
// baseline (244.227 us; speedup 1.0000x reference)
//
#include <hip/hip_runtime.h>
#include <hip/hip_bf16.h>

// Causal attention, B=4 S=2048 E=1024 D=1024, fp32 in/out.
// Round 9: (a) scores split-K into two 512 halves -> bf16 partials sc0/sc1
// (1088 blocks, halved block latency; softmax sums the two), (b) PV combine
// kernel replaced by hipMemsetAsync(heavy half)=0 + unsafeAtomicAdd stores
// for m>=8 tiles (2 addends/address, deterministic). QKV/core unchanged.

typedef unsigned short u16;
typedef __attribute__((ext_vector_type(4))) u16   u16x4;
typedef __attribute__((ext_vector_type(8))) u16   u16x8;
typedef __attribute__((ext_vector_type(8))) short short8;
typedef __attribute__((ext_vector_type(4))) float f32x4;
typedef __attribute__((ext_vector_type(4))) int   i32x4;

__device__ inline u16 f2b(float v) {
    __hip_bfloat16 b = __float2bfloat16(v);
    return *reinterpret_cast<u16*>(&b);
}
__device__ inline float b2f(u16 v) {
    unsigned int u = ((unsigned int)v) << 16;
    return *reinterpret_cast<float*>(&u);
}

template <typename T> __device__ inline void store_elem(T* p, float v);
template <> __device__ inline void store_elem<float>(float* p, float v) { *p = v; }
template <> __device__ inline void store_elem<u16>(u16* p, float v)     { *p = f2b(v); }

// async global->LDS 16B per lane; LDS dest must be wave-uniform base + lane*16
__device__ inline void gload_lds16(const u16* g, u16* l) {
    __builtin_amdgcn_global_load_lds(
        (const __attribute__((address_space(1))) void*)g,
        (__attribute__((address_space(3))) void*)l, 16, 0, 0);
}

// ---------------- merged fp32 -> bf16 cast: [x | wq | wk | wv] -------------
__global__ __launch_bounds__(256) void cast_all_kernel(
    const float* __restrict__ x,  const float* __restrict__ wq,
    const float* __restrict__ wk, const float* __restrict__ wv,
    u16* __restrict__ dst) {
    int q = blockIdx.x * 256 + threadIdx.x;     // quad index, 2883584 total
    const float* src;
    int sidx;
    if (q < 2097152) { src = x; sidx = q * 4; }
    else {
        int qq = q - 2097152;
        int w  = qq >> 18;                      // 262144 quads per weight
        sidx   = (qq & 262143) * 4;
        src    = (w == 0) ? wq : (w == 1) ? wk : wv;
    }
    float4 v = *(const float4*)(src + sidx);
    u16x4 o;
    o.x = f2b(v.x); o.y = f2b(v.y); o.z = f2b(v.z); o.w = f2b(v.w);
    *(u16x4*)(dst + q * 4) = o;
}

// ---------------- BT-GEMM core -----------------------------------------------
#define MT 128
#define NT 128
#define BKH 32
#define HSZ (MT * BKH)   // elems per half buffer = 4096

// As/Bs caller-provided so multiple instantiations share one LDS allocation.
// TRANS=0: plain store. TRANS=1: transposed bf16 store into vt[b][d][s].
// TRANS=2: fp32 unsafeAtomicAdd into C (for PV split-K accumulation).
template <int TRANS, typename OutT>
__device__ __forceinline__ void gemm_core(
    u16* __restrict__ As, u16* __restrict__ Bs,
    const u16* __restrict__ Ab, int lda,
    const u16* __restrict__ Bb, int ldb,
    OutT* __restrict__ Cb, int ldc,
    int m0, int n0, int kbeg, int kend)
{
    const int tid  = threadIdx.x;
    const int lane = tid & 63;
    const int wave = tid >> 6;
    const int quad = lane >> 4;
    const int r16  = lane & 15;
    const int mw   = (wave >> 1) * 64;
    const int nw   = (wave & 1) * 64;

    const int c0 = tid, c1 = tid + 256;
    const int r0 = c0 >> 2, k0 = (c0 & 3) * 8;
    const int r1 = c1 >> 2, k1 = (c1 & 3) * 8;
    const int oa0 = (m0 + r0) * lda + k0;
    const int oa1 = (m0 + r1) * lda + k1;
    const int ob0 = (n0 + r0) * ldb + k0;
    const int ob1 = (n0 + r1) * ldb + k1;

    f32x4 acc[4][4] = {};

    for (int kk = kbeg; kk < kend; kk += 2 * BKH) {
        __syncthreads();
        gload_lds16(Ab + (kk + oa0),        &As[c0 * 8]);
        gload_lds16(Ab + (kk + oa1),        &As[c1 * 8]);
        gload_lds16(Ab + (kk + BKH + oa0),  &As[HSZ + c0 * 8]);
        gload_lds16(Ab + (kk + BKH + oa1),  &As[HSZ + c1 * 8]);
        gload_lds16(Bb + (kk + ob0),        &Bs[c0 * 8]);
        gload_lds16(Bb + (kk + ob1),        &Bs[c1 * 8]);
        gload_lds16(Bb + (kk + BKH + ob0),  &Bs[HSZ + c0 * 8]);
        gload_lds16(Bb + (kk + BKH + ob1),  &Bs[HSZ + c1 * 8]);
        __syncthreads();

#pragma unroll
        for (int h = 0; h < 2; h++) {
            short8 af[4], bf[4];
#pragma unroll
            for (int i = 0; i < 4; i++)
                af[i] = *(const short8*)&As[h * HSZ + (mw + i * 16 + r16) * BKH + quad * 8];
#pragma unroll
            for (int j = 0; j < 4; j++)
                bf[j] = *(const short8*)&Bs[h * HSZ + (nw + j * 16 + r16) * BKH + quad * 8];
#pragma unroll
            for (int i = 0; i < 4; i++)
#pragma unroll
                for (int j = 0; j < 4; j++)
                    acc[i][j] = __builtin_amdgcn_mfma_f32_16x16x32_bf16(af[i], bf[j], acc[i][j], 0, 0, 0);
        }
    }

    // epilogue: C/D layout col=lane&15, row=quad*4+reg
    if (TRANS == 0 || TRANS == 2) {
#pragma unroll
        for (int i = 0; i < 4; i++)
#pragma unroll
            for (int j = 0; j < 4; j++)
#pragma unroll
                for (int r = 0; r < 4; r++) {
                    int m = m0 + mw + i * 16 + quad * 4 + r;
                    int n = n0 + nw + j * 16 + r16;
                    if (TRANS == 0)
                        store_elem(&Cb[(long long)m * ldc + n], acc[i][j][r]);
                    else
                        unsafeAtomicAdd((float*)&Cb[(long long)m * ldc + n],
                                        acc[i][j][r]);
                }
    } else {
#pragma unroll
        for (int i = 0; i < 4; i++)
#pragma unroll
            for (int j = 0; j < 4; j++) {
                int mbase = m0 + mw + i * 16 + quad * 4;      // 4-aligned
                int d     = n0 + nw + j * 16 + r16;
                int b     = mbase >> 11;
                int s     = mbase & 2047;
                u16x4 o;
#pragma unroll
                for (int r = 0; r < 4; r++) o[r] = f2b(acc[i][j][r]);
                *(u16x4*)((u16*)Cb + (((b << 10) + d) * 2048 + s)) = o;
            }
    }
}

// QKV: [8192,1024] x [3072,1024]^T. Blocks x<16 -> qk[8192,2048] (Q|K dense);
// x>=16 -> V, stored transposed into vt[b][d][s].
__global__ __launch_bounds__(256, 4) void gemm_qkv(
    const u16* __restrict__ xb, const u16* __restrict__ wb,
    u16* __restrict__ qk, u16* __restrict__ vt) {
    __shared__ __align__(16) u16 As[2 * HSZ];
    __shared__ __align__(16) u16 Bs[2 * HSZ];
    int bx = blockIdx.x, m0 = blockIdx.y * MT;
    if (bx < 16)
        gemm_core<0, u16>(As, Bs, xb, 1024, wb, 1024, qk, 2048,
                          m0, bx * 128, 0, 1024);
    else
        gemm_core<1, u16>(As, Bs, xb, 1024, wb + 2048 * 1024, 1024, vt, 2048,
                          m0, (bx - 16) * 128, 0, 1024);
}

// scores split-K: blockIdx.x = 2*tri_tile + khalf; each half writes its own
// bf16 partial buffer (summed in softmax).
__global__ __launch_bounds__(256, 4) void gemm_scores(
    const u16* __restrict__ qk, u16* __restrict__ sc0, u16* __restrict__ sc1) {
    __shared__ __align__(16) u16 As[2 * HSZ];
    __shared__ __align__(16) u16 Bs[2 * HSZ];
    int bx = blockIdx.x;
    int t = bx >> 1, half = bx & 1;
    float ff = sqrtf(8.0f * t + 1.0f);
    int m = (int)((ff - 1.0f) * 0.5f);
    while ((m + 1) * (m + 2) / 2 <= t) m++;
    while (m * (m + 1) / 2 > t) m--;
    int m0 = m * MT;
    int n0 = (t - m * (m + 1) / 2) * NT;
    const u16* Ab = qk + (long long)blockIdx.z * 2048 * 2048;
    const u16* Bb = Ab + 1024;
    u16* Cb = (half ? sc1 : sc0) + (long long)blockIdx.z * 2048 * 2048;
    gemm_core<0, u16>(As, Bs, Ab, 2048, Bb, 2048, Cb, 2048,
                      m0, n0, half * 512, half * 512 + 512);
}

// PV split-K, longest-first schedule: per batch 192 units (see round 5).
// m<8: sole writer, plain store. m>=8 (chunk0 and chunk1): unsafeAtomicAdd
// onto the pre-zeroed heavy half of out.
__global__ __launch_bounds__(256, 4) void gemm_pv(
    const u16* __restrict__ P, const u16* __restrict__ vt,
    float* __restrict__ out)
{
    __shared__ __align__(16) u16 As[2 * HSZ];
    __shared__ __align__(16) u16 Bs[2 * HSZ];
    const int bid = blockIdx.x;
    int m, chunk, n;
    if (bid < 80) {                       // K = 1024 class
        int q = bid >> 3; n = bid & 7;
        if (q < 9) { m = 7 + q; chunk = 0; } else { m = 15; chunk = 1; }
    } else {                              // K = s*128, s = 7..1
        int r = bid - 80; int s = 7 - (r >> 4); int t = r & 15;
        n = t & 7;
        if (t < 8) { m = s - 1; chunk = 0; } else { m = s + 7; chunk = 1; }
    }
    const int m0 = m * MT, n0 = n * NT;
    const int kbeg = chunk ? 1024 : 0;
    const int kend = chunk ? (m0 + MT) : min(1024, m0 + MT);
    const int b = blockIdx.z;

    const u16* Ab = P  + (long long)b * 2048 * 2048;
    const u16* Bb = vt + (long long)b * 1024 * 2048;
    float* Cb = out + (long long)b * 2097152;
    if (m < 8)
        gemm_core<0, float>(As, Bs, Ab, 2048, Bb, 2048, Cb, 1024,
                            m0, n0, kbeg, kend);
    else
        gemm_core<2, float>(As, Bs, Ab, 2048, Bb, 2048, Cb, 1024,
                            m0, n0, kbeg, kend);
}

// ---------------- single-pass causal softmax (bf16 partials -> bf16 P) -----
// logits = sc0 + sc1 (split-K partial sums); triangle-trimmed IO.
__global__ __launch_bounds__(256) void softmax_kernel(const u16* __restrict__ sc0,
                                                      const u16* __restrict__ sc1,
                                                      u16* __restrict__ P) {
    const int S = 2048;
    int row = blockIdx.x;            // b*S + i
    int i   = row & (S - 1);
    int n   = i + 1;
    int kendr = (i & ~127) + 128;
    const u16* s0row = sc0 + (long long)row * S;
    const u16* s1row = sc1 + (long long)row * S;
    u16*       prow  = P   + (long long)row * S;

    int j0 = threadIdx.x * 8;
    u16x8 raw0 = {}, raw1 = {};
    if (j0 <= i) {
        raw0 = *(const u16x8*)(s0row + j0);
        raw1 = *(const u16x8*)(s1row + j0);
    }
    float v[8];
#pragma unroll
    for (int e = 0; e < 8; e++)
        v[e] = (j0 + e < n) ? b2f(raw0[e]) + b2f(raw1[e]) : -1e30f;

    __shared__ float red[8];
    float lmax = v[0];
#pragma unroll
    for (int e = 1; e < 8; e++) lmax = fmaxf(lmax, v[e]);
    for (int o = 32; o > 0; o >>= 1) lmax = fmaxf(lmax, __shfl_xor(lmax, o, 64));
    int wid = threadIdx.x >> 6;
    if ((threadIdx.x & 63) == 0) red[wid] = lmax;
    __syncthreads();
    float Mx = fmaxf(fmaxf(red[0], red[1]), fmaxf(red[2], red[3]));

    // exp((s-Mx)/32) = exp2((s-Mx) * (1/(32 ln2)))
    const float C = 0.045112384f;
    float ev[8];
    float lsum = 0.f;
#pragma unroll
    for (int e = 0; e < 8; e++) {
        ev[e] = (j0 + e < n) ? exp2f((v[e] - Mx) * C) : 0.f;
        lsum += ev[e];
    }
    for (int o = 32; o > 0; o >>= 1) lsum += __shfl_xor(lsum, o, 64);
    if ((threadIdx.x & 63) == 0) red[4 + wid] = lsum;
    __syncthreads();
    float inv = 1.0f / (red[4] + red[5] + red[6] + red[7]);

    if (j0 < kendr) {
        u16x8 o8;
#pragma unroll
        for (int e = 0; e < 8; e++) o8[e] = f2b(ev[e] * inv);
        *(u16x8*)(prow + j0) = o8;
    }
}

extern "C" void kernel_launch(void* const* d_in, const int* in_sizes, int n_in,
                              void* d_out, int out_size, void* d_ws, size_t ws_size,
                              hipStream_t stream) {
    const float* x  = (const float*)d_in[0];
    const float* wq = (const float*)d_in[1];
    const float* wk = (const float*)d_in[2];
    const float* wv = (const float*)d_in[3];
    float* out = (float*)d_out;

    char* ws = (char*)d_ws;
    // layout: xb 16M | wb 6M | qk 32M | sc0 32M | sc1 32M | P 32M | vt 16M
    u16* xb  = (u16*)(ws);
    u16* wb  = (u16*)(ws + 16777216LL);
    u16* qk  = (u16*)(ws + 23068672LL);
    u16* sc0 = (u16*)(ws + 56623104LL);
    u16* sc1 = (u16*)(ws + 90177536LL);
    u16* P   = (u16*)(ws + 123731968LL);
    u16* vt  = (u16*)(ws + 157286400LL);   // total 174,063,616 bytes

    // 1. casts (x + 3 weights, one dispatch)
    cast_all_kernel<<<11264, 256, 0, stream>>>(x, wq, wk, wv, xb);

    // zero the heavy half of out (rows 1024..2047 per batch) for atomic acc
    for (int b = 0; b < 4; b++)
        hipMemsetAsync(out + (long long)b * 2097152 + 1048576, 0,
                       4194304, stream);

    // 2. QKV projection (V stored transposed; Q,K packed [8192,2048])
    gemm_qkv<<<dim3(24, 64, 1), 256, 0, stream>>>(xb, wb, qk, vt);

    // 3. scores split-K halves -> bf16 partials (272 blocks/batch)
    gemm_scores<<<dim3(272, 1, 4), 256, 0, stream>>>(qk, sc0, sc1);

    // 4. single-pass causal softmax over sc0+sc1 -> P bf16
    softmax_kernel<<<8192, 256, 0, stream>>>(sc0, sc1, P);

    // 5. PV split-K; m>=8 accumulates via HW fp32 atomics
    gemm_pv<<<dim3(192, 1, 4), 256, 0, stream>>>(P, vt, out);
}